// Round 4
// baseline (335.717 us; speedup 1.0000x reference)
//
#include <hip/hip_runtime.h>
#include <cmath>

#define TPB 256
typedef float floatx4 __attribute__((ext_vector_type(4)));
typedef __bf16 bf16x8 __attribute__((ext_vector_type(8)));
typedef unsigned short ushort8 __attribute__((ext_vector_type(8)));
typedef unsigned short ushort_t;

// ---------- workspace layout ----------
// float units: [0]=sc2 (S_N1*s_w2), [1]=sc3 (S_N2*s_w3), [2]=K1 (S_X1*s_w1/S_N1)
// uint units 4..15: enc min/max (6 pairs)
#define OFF_B1 520       // 20  f32  (pre-divided by S_N1)
#define OFF_B2 544       // 50  f32
#define OFF_B3 600       // 500 f32
#define W1BF_BYTE 6144       // [32][32] u16 int weights (conv1)
#define W2BF_BYTE 8192       // [20 chunks][64 co][32 k] u16 int weights (conv2), 81920 B
#define W3BF_BYTE 131072     // [512][800]  u16 int weights (fc1)
#define Q1_BYTE  1048576ULL  // [B][pixel(144)][ci(20)] bf16 (channels-last)
#define Q2_BYTE  25165824ULL // [B][800] bf16
#define Q3_BYTE  33554432ULL // [B][500] u8

#define S_X1 (3.5f/255.0f)
#define ZP_X1 36.0f
#define S_N1 (6.0f/255.0f)
#define S_N2 (8.0f/255.0f)
#define S_N3 (10.0f/255.0f)

#define CONV2_G 8

__device__ inline unsigned int enc_f(float f){
    unsigned int u = __float_as_uint(f);
    return (u & 0x80000000u) ? ~u : (u | 0x80000000u);
}
__device__ inline float dec_f(unsigned int e){
    unsigned int u = (e & 0x80000000u) ? (e & 0x7fffffffu) : ~e;
    return __uint_as_float(u);
}
__device__ inline void sczp(float mn, float mx, float& s, float& zp){
    s = (mx - mn) / 255.0f;
    zp = truncf(fminf(fmaxf(0.0f - mn / s, 0.0f), 255.0f));
}
__device__ inline float qclip(float x, float s, float zp){
    return rintf(fminf(fmaxf(zp + x / s, 0.0f), 255.0f));
}
// exact bf16 bits for integer-valued floats |v| < 256
__device__ inline ushort_t bfbits(float v){
    return (ushort_t)(__float_as_uint(v) >> 16);
}

__global__ void k_init(unsigned int* enc){
    int i = threadIdx.x;
    if (i < 6){ enc[2*i] = 0xFFFFFFFFu; enc[2*i+1] = 0u; }
}

__global__ __launch_bounds__(TPB) void k_minmax(
        const float* c1w, const float* c1b, const float* c2w, const float* c2b,
        const float* f1w, const float* f1b, unsigned int* enc){
    __shared__ float smn[TPB], smx[TPB];
    int bb = blockIdx.x, tid = threadIdx.x;
    const float* src; int n, t, sub, nsub;
    if      (bb == 0){ src=c1w; n=500;    t=0; sub=0;     nsub=1;  }
    else if (bb == 1){ src=c1b; n=20;     t=1; sub=0;     nsub=1;  }
    else if (bb <  6){ src=c2w; n=25000;  t=2; sub=bb-2;  nsub=4;  }
    else if (bb == 6){ src=c2b; n=50;     t=3; sub=0;     nsub=1;  }
    else if (bb < 71){ src=f1w; n=400000; t=4; sub=bb-7;  nsub=64; }
    else             { src=f1b; n=500;    t=5; sub=0;     nsub=1;  }
    float mn = INFINITY, mx = -INFINITY;
    for (int i = sub*TPB + tid; i < n; i += nsub*TPB){
        float v = src[i]; mn = fminf(mn, v); mx = fmaxf(mx, v);
    }
    smn[tid] = mn; smx[tid] = mx; __syncthreads();
    for (int s = TPB/2; s > 0; s >>= 1){
        if (tid < s){
            smn[tid] = fminf(smn[tid], smn[tid+s]);
            smx[tid] = fmaxf(smx[tid], smx[tid+s]);
        }
        __syncthreads();
    }
    if (tid == 0){
        atomicMin(&enc[2*t],   enc_f(smn[0]));
        atomicMax(&enc[2*t+1], enc_f(smx[0]));
    }
}

// w2bt chunk packing (20 chunks of K=32):
//   main c in 0..12:   oct q -> tap = 2c + (q>>1), ci = (q&1)*8 + jj   (tap 25 -> zero)
//   residue c in 13..19: oct q -> tap = 4(c-13) + q, ci = 16 + jj (jj<4; jj>=4 -> zero)
#define N_EFF 452157
__global__ __launch_bounds__(TPB) void k_make_eff(
        const float* c1w, const float* c1b, const float* c2w, const float* c2b,
        const float* f1w, const float* f1b, const unsigned int* enc,
        float* ws, ushort_t* w1bf, ushort_t* w2bf, ushort_t* w3bf){
    int i = blockIdx.x * TPB + threadIdx.x;
    if (i >= N_EFF) return;
    if (i < 1024){                   // w1bf: [n(32)][k(32)] integer weights
        int n = i >> 5, k = i & 31;
        float v = 0.0f;
        if (n < 20 && k < 25){
            float s, zp; sczp(dec_f(enc[0]), dec_f(enc[1]), s, zp);
            v = qclip(c1w[n*25 + k], s, zp) - zp;
        }
        w1bf[i] = bfbits(v);
    } else if (i < 1044){            // b1 pre-divided by S_N1
        int j = i - 1024;
        float s, zp; sczp(dec_f(enc[2]), dec_f(enc[3]), s, zp);
        ws[OFF_B1 + j] = (s * (qclip(c1b[j], s, zp) + zp)) / S_N1;
    } else if (i < 42004){           // w2bt chunk-packed
        int j = i - 1044;
        int c = j >> 11, r = j & 2047, co = r >> 5, k = r & 31;
        int q = k >> 3, jj = k & 7;
        int tap, ci; bool valid;
        if (c < 13){ tap = 2*c + (q>>1); ci = (q&1)*8 + jj; valid = (tap < 25); }
        else       { tap = 4*(c-13) + q; ci = 16 + jj;      valid = (tap < 25) && (jj < 4); }
        valid = valid && (co < 50);
        float v = 0.0f;
        if (valid){
            float s, zp; sczp(dec_f(enc[4]), dec_f(enc[5]), s, zp);
            v = qclip(c2w[(co*20 + ci)*25 + tap], s, zp) - zp;
        }
        w2bf[j] = bfbits(v);
    } else if (i < 42054){
        int j = i - 42004;
        float s, zp; sczp(dec_f(enc[6]), dec_f(enc[7]), s, zp);
        ws[OFF_B2 + j] = s * (qclip(c2b[j], s, zp) + zp);
    } else if (i < 451654){          // w3bf: [n(512)][k(800)]
        int j = i - 42054;
        int n = j / 800, k = j - 800*n;
        float v = 0.0f;
        if (n < 500){
            float s, zp; sczp(dec_f(enc[8]), dec_f(enc[9]), s, zp);
            v = qclip(f1w[n*800 + k], s, zp) - zp;
        }
        w3bf[j] = bfbits(v);
    } else if (i < 452154){
        int j = i - 451654;
        float s, zp; sczp(dec_f(enc[10]), dec_f(enc[11]), s, zp);
        ws[OFF_B3 + j] = s * (qclip(f1b[j], s, zp) + zp);
    } else if (i == 452154){
        float s, zp; sczp(dec_f(enc[4]), dec_f(enc[5]), s, zp);
        ws[0] = S_N1 * s;            // conv2 combined scale
    } else if (i == 452155){
        float s, zp; sczp(dec_f(enc[8]), dec_f(enc[9]), s, zp);
        ws[1] = S_N2 * s;            // fc1 combined scale
    } else {
        float s, zp; sczp(dec_f(enc[0]), dec_f(enc[1]), s, zp);
        ws[2] = (S_X1 * s) / S_N1;   // conv1 combined scale, pre-divided
    }
}

// conv1 via bf16 MFMA implicit GEMM -> channels-last q1cl[B][pixel(144)][ci(20)] bf16 ints
__global__ __launch_bounds__(TPB) void k_conv1(const float* x, const ushort_t* w1bf,
                                               const float* ws, ushort_t* q1cl){
    __shared__ ushort_t xs[784];
    __shared__ unsigned char hb[5760];   // [oh(24)*12+pw][ch(20)] horizontal pool maxes
    int b = blockIdx.x, tid = threadIdx.x;
    int lane = tid & 63, wv = tid >> 6;
    int ln = lane & 15, quad = lane >> 4;

    const float* xb = x + (size_t)b * 784;
    for (int i = tid; i < 784; i += TPB){
        float v = xb[i];
        float q = rintf(fminf(fmaxf(ZP_X1 + v / S_X1, 0.0f), 255.0f));
        xs[i] = bfbits(q - ZP_X1);
    }

    int offj[8]; bool vj[8];
    #pragma unroll
    for (int j = 0; j < 8; ++j){
        int k = quad*8 + j;
        vj[j] = (k < 25);
        int kh = k / 5, kw = k - 5*kh;
        offj[j] = vj[j] ? (kh*28 + kw) : 0;
    }

    ushort8 bw0 = *(const ushort8*)(w1bf + ln*32 + quad*8);
    ushort8 bw1 = *(const ushort8*)(w1bf + (16 + ln)*32 + quad*8);
    bf16x8 bf0 = __builtin_bit_cast(bf16x8, bw0);
    bf16x8 bf1 = __builtin_bit_cast(bf16x8, bw1);

    float K1 = ws[2];
    float B1_0 = ws[OFF_B1 + ln];
    float B1_1 = (ln < 4) ? ws[OFF_B1 + 16 + ln] : 0.0f;
    __syncthreads();

    for (int i = 0; i < 9; ++i){
        int mt = 9*wv + i;
        int m = mt*16 + ln;
        int oh = m / 24, ow = m - 24*oh;
        int base = oh*28 + ow;
        ushort8 aw;
        #pragma unroll
        for (int j = 0; j < 8; ++j)
            aw[j] = vj[j] ? xs[base + offj[j]] : (ushort_t)0;
        bf16x8 af = __builtin_bit_cast(bf16x8, aw);
        floatx4 z = (floatx4){0.f,0.f,0.f,0.f};
        floatx4 a0 = __builtin_amdgcn_mfma_f32_16x16x32_bf16(af, bf0, z, 0, 0, 0);
        floatx4 a1 = __builtin_amdgcn_mfma_f32_16x16x32_bf16(af, bf1, z, 0, 0, 0);

        int m0 = mt*16 + quad*4;
        int oh0 = m0 / 24, owp = (m0 - 24*oh0) >> 1;
        int hbase = (oh0*12 + owp)*20;
        {
            float q[4];
            #pragma unroll
            for (int r = 0; r < 4; ++r){
                float y = fmaxf(fmaf(a0[r], K1, B1_0), 0.0f);
                q[r] = fmodf(rintf(y), 256.0f);
            }
            hb[hbase + ln]      = (unsigned char)fmaxf(q[0], q[1]);
            hb[hbase + 20 + ln] = (unsigned char)fmaxf(q[2], q[3]);
        }
        if (ln < 4){
            float q[4];
            #pragma unroll
            for (int r = 0; r < 4; ++r){
                float y = fmaxf(fmaf(a1[r], K1, B1_1), 0.0f);
                q[r] = fmodf(rintf(y), 256.0f);
            }
            hb[hbase + 16 + ln]      = (unsigned char)fmaxf(q[0], q[1]);
            hb[hbase + 36 + ln]      = (unsigned char)fmaxf(q[2], q[3]);
        }
    }
    __syncthreads();

    // vertical pool + write CHANNELS-LAST: o = pixel*20 + c
    for (int o = tid; o < 2880; o += TPB){
        int p = o / 20, c = o - 20*p;
        int ph = p / 12, pw = p - 12*ph;
        unsigned char t_ = hb[((2*ph)*12 + pw)*20 + c];
        unsigned char u_ = hb[((2*ph+1)*12 + pw)*20 + c];
        float m_ = (float)(t_ > u_ ? t_ : u_);
        q1cl[(size_t)b*2880 + o] = bfbits(m_);
    }
}

// conv2 v3: channels-last LDS image, 20 K-chunks split across 4 waves (read-once),
// B-frags in registers, barrier-free K-loop, LDS partial-sum reduce, G images/block.
__global__ __launch_bounds__(TPB) void k_conv2(const ushort_t* q1cl, const ushort_t* w2bt,
                                               const float* ws, ushort_t* q2bf, int B){
    __shared__ __align__(16) ushort_t xs[236*24];     // [pixel][ci24], pixels 144..235 = zeros
    __shared__ __align__(16) float rbufA[16*64*4];
    __shared__ __align__(16) float rbufB[16*64*4];
    int tid = threadIdx.x;
    int lane = tid & 63, wv = tid >> 6;
    int ln = lane & 15, quad = lane >> 4;

    // zero xs fully (pad ci and zero-pixel region) — once per block
    for (int i = tid; i < 236*12; i += TPB) ((unsigned int*)xs)[i] = 0u;

    // per-lane A addressing (u16 units): addr = abase[mt] + aoff[cc]
    int abase[4];
    #pragma unroll
    for (int mt = 0; mt < 4; ++mt)
        abase[mt] = (24*mt + (ln>>3)*12 + (ln&7)) * 24;
    int aoff[5];
    #pragma unroll
    for (int cc = 0; cc < 5; ++cc){
        int c = wv*5 + cc;
        int tap, inner;
        if (c < 13){ tap = 2*c + (quad>>1); inner = (quad&1)*8; }
        else       { tap = 4*(c-13) + quad; inner = 16; }
        int pt = 144;
        if (tap < 25){ int kh = tap/5, kw = tap-5*kh; pt = kh*12 + kw; }
        aoff[cc] = pt*24 + inner;
    }

    // B-frags: this wave's 5 chunks x 4 nt, loaded once, live in VGPRs
    ushort8 Bf[5][4];
    #pragma unroll
    for (int cc = 0; cc < 5; ++cc){
        int c = wv*5 + cc;
        #pragma unroll
        for (int nt = 0; nt < 4; ++nt)
            Bf[cc][nt] = *(const ushort8*)(w2bt + (size_t)(c*64 + nt*16 + ln)*32 + quad*8);
    }

    float sc2 = ws[0];
    int co[4]; float bias[4];
    #pragma unroll
    for (int nt = 0; nt < 4; ++nt){
        co[nt] = nt*16 + ln;
        bias[nt] = (co[nt] < 50) ? ws[OFF_B2 + co[nt]] : 0.0f;
    }

    int b0 = blockIdx.x * CONV2_G;
    // stage image 0 (all threads)
    {
        const unsigned int* src = (const unsigned int*)(q1cl + (size_t)b0*2880);
        for (int i = tid; i < 1440; i += TPB){
            int p = i / 10, d = i - 10*p;
            ((unsigned int*)xs)[p*12 + d] = src[i];
        }
    }
    __syncthreads();

    for (int g = 0; g < CONV2_G; ++g){
        int b = b0 + g;
        if (b >= B) break;

        floatx4 acc[4][4];
        #pragma unroll
        for (int mt = 0; mt < 4; ++mt)
            #pragma unroll
            for (int nt = 0; nt < 4; ++nt) acc[mt][nt] = (floatx4){0.f,0.f,0.f,0.f};

        // barrier-free K-loop: 20 A-reads + 80 MFMAs per wave
        #pragma unroll
        for (int cc = 0; cc < 5; ++cc){
            #pragma unroll
            for (int mt = 0; mt < 4; ++mt){
                ushort8 aw = *(const ushort8*)(xs + abase[mt] + aoff[cc]);
                bf16x8 af = __builtin_bit_cast(bf16x8, aw);
                #pragma unroll
                for (int nt = 0; nt < 4; ++nt)
                    acc[mt][nt] = __builtin_amdgcn_mfma_f32_16x16x32_bf16(
                                      af, __builtin_bit_cast(bf16x8, Bf[cc][nt]), acc[mt][nt], 0, 0, 0);
            }
        }
        __syncthreads();   // A: xs + rbufs free

        // phase 1: waves 1,3 dump partials; waves 0,2 stage next image
        if (wv == 1 || wv == 3){
            float* rb = (wv == 1) ? rbufA : rbufB;
            #pragma unroll
            for (int mt = 0; mt < 4; ++mt)
                #pragma unroll
                for (int nt = 0; nt < 4; ++nt)
                    *(floatx4*)(rb + ((mt*4+nt)*64 + lane)*4) = acc[mt][nt];
        } else if (g + 1 < CONV2_G && b + 1 < B){
            const unsigned int* src = (const unsigned int*)(q1cl + (size_t)(b+1)*2880);
            int sid = (wv == 0) ? lane : 64 + lane;
            for (int i = sid; i < 1440; i += 128){
                int p = i / 10, d = i - 10*p;
                ((unsigned int*)xs)[p*12 + d] = src[i];
            }
        }
        __syncthreads();   // B

        // phase 2: pairwise add + cross-exchange
        if (wv == 0){
            #pragma unroll
            for (int mt = 0; mt < 4; ++mt)
                #pragma unroll
                for (int nt = 0; nt < 4; ++nt)
                    acc[mt][nt] += *(floatx4*)(rbufA + ((mt*4+nt)*64 + lane)*4);
            #pragma unroll
            for (int mt = 2; mt < 4; ++mt)
                #pragma unroll
                for (int nt = 0; nt < 4; ++nt)
                    *(floatx4*)(rbufA + ((mt*4+nt)*64 + lane)*4) = acc[mt][nt];
        } else if (wv == 2){
            #pragma unroll
            for (int mt = 0; mt < 4; ++mt)
                #pragma unroll
                for (int nt = 0; nt < 4; ++nt)
                    acc[mt][nt] += *(floatx4*)(rbufB + ((mt*4+nt)*64 + lane)*4);
            #pragma unroll
            for (int mt = 0; mt < 2; ++mt)
                #pragma unroll
                for (int nt = 0; nt < 4; ++nt)
                    *(floatx4*)(rbufB + ((mt*4+nt)*64 + lane)*4) = acc[mt][nt];
        }
        __syncthreads();   // C

        // final add + epilogue: wave0 owns mt 0,1; wave2 owns mt 2,3
        if (wv == 0 || wv == 2){
            int m0 = (wv == 0) ? 0 : 2;
            const float* rb = (wv == 0) ? rbufB : rbufA;
            #pragma unroll
            for (int mi = 0; mi < 2; ++mi){
                int mt = m0 + mi;
                #pragma unroll
                for (int nt = 0; nt < 4; ++nt){
                    floatx4 a = acc[mt][nt];
                    a += *(floatx4*)(rb + ((mt*4+nt)*64 + lane)*4);
                    float q[4];
                    #pragma unroll
                    for (int r = 0; r < 4; ++r){
                        float y = fmaxf((a[r]*sc2 + bias[nt]) / S_N2, 0.0f);
                        q[r] = fmodf(rintf(y), 256.0f);
                    }
                    float h0 = fmaxf(q[0], q[1]), h1 = fmaxf(q[2], q[3]);
                    float v0 = fmaxf(h0, __shfl_xor(h0, 32));
                    float v1 = fmaxf(h1, __shfl_xor(h1, 32));
                    if (quad < 2 && co[nt] < 50){
                        size_t base = (size_t)b*800 + co[nt]*16 + mt*4 + quad*2;
                        q2bf[base]     = bfbits(v0);
                        q2bf[base + 1] = bfbits(v1);
                    }
                }
            }
        }
        __syncthreads();   // D: rbuf reads done before next phase-1 writes
    }
}

// fc1 via bf16 MFMA GEMM: [B,800] x [512,800]^T, tile 64x64, K-chunk 32, dbuf LDS.
__global__ __launch_bounds__(TPB) void k_fc1(const ushort_t* q2bf, const ushort_t* w3bf,
                                             const float* ws, unsigned char* q3, int B){
    __shared__ ushort_t As[2][64*40];
    int tid = threadIdx.x;
    int n0b = blockIdx.x * 64;
    int b0  = blockIdx.y * 64;
    int lane = tid & 63, wv = tid >> 6;
    int ln = lane & 15, quad = lane >> 4;
    int n0 = n0b + wv*16;
    int lrow = tid >> 2, lk = (tid & 3) * 8;
    const ushort_t* asrc = q2bf + (size_t)(b0 + lrow)*800 + lk;
    ushort_t* adst0 = &As[0][0] + lrow*40 + lk;
    ushort_t* adst1 = &As[1][0] + lrow*40 + lk;

    floatx4 acc[4];
    #pragma unroll
    for (int mt = 0; mt < 4; ++mt) acc[mt] = (floatx4){0.f,0.f,0.f,0.f};

    *(ushort8*)adst0 = *(const ushort8*)asrc;
    __syncthreads();

    for (int c = 0; c < 25; ++c){
        const ushort_t* cur = &As[c & 1][0];
        ushort8 tn;
        bool pf = (c + 1 < 25);
        if (pf) tn = *(const ushort8*)(asrc + (c + 1)*32);
        ushort8 bw = *(const ushort8*)(w3bf + (size_t)(n0 + ln)*800 + c*32 + quad*8);
        bf16x8 bfr = __builtin_bit_cast(bf16x8, bw);
        #pragma unroll
        for (int mt = 0; mt < 4; ++mt){
            ushort8 aw = *(const ushort8*)(cur + (16*mt + ln)*40 + quad*8);
            acc[mt] = __builtin_amdgcn_mfma_f32_16x16x32_bf16(
                          __builtin_bit_cast(bf16x8, aw), bfr, acc[mt], 0, 0, 0);
        }
        if (pf) *(ushort8*)(((c + 1) & 1) ? adst1 : adst0) = tn;
        __syncthreads();
    }

    float sc3 = ws[1];
    int n = n0 + ln;
    if (n < 500){
        float bias = ws[OFF_B3 + n];
        #pragma unroll
        for (int mt = 0; mt < 4; ++mt){
            #pragma unroll
            for (int r = 0; r < 4; ++r){
                int m = 16*mt + 4*quad + r;
                float y = fmaxf((acc[mt][r] * sc3 + bias) / S_N3, 0.0f);
                float q = fmodf(rintf(y), 256.0f);
                q3[(size_t)(b0 + m)*500 + n] = (unsigned char)q;
            }
        }
    }
}

// fc2 (dequant + [B,500]x[10,500]^T + bias) + log_softmax. 16 rows/block, w2 in LDS.
__global__ __launch_bounds__(TPB) void k_fc2(const unsigned char* q3, const float* w2,
                                             const float* b2, float* out, int B){
    __shared__ float w2s[5000];
    __shared__ float b2s[10];
    int tid = threadIdx.x;
    for (int i = tid; i < 5000; i += TPB) w2s[i] = w2[i];
    if (tid < 10) b2s[tid] = b2[tid];
    __syncthreads();
    int lane = tid & 63, wv = tid >> 6;
    for (int rr = 0; rr < 4; ++rr){
        int b = blockIdx.x*16 + wv*4 + rr;
        if (b >= B) break;
        float acc[10];
        #pragma unroll
        for (int c = 0; c < 10; ++c) acc[c] = 0.0f;
        for (int k = lane; k < 500; k += 64){
            float xf = S_N3 * (float)q3[(size_t)b*500 + k];
            #pragma unroll
            for (int c = 0; c < 10; ++c)
                acc[c] = fmaf(xf, w2s[c*500 + k], acc[c]);
        }
        #pragma unroll
        for (int off = 32; off > 0; off >>= 1)
            #pragma unroll
            for (int c = 0; c < 10; ++c)
                acc[c] += __shfl_xor(acc[c], off);
        float lg[10], m = -INFINITY;
        #pragma unroll
        for (int c = 0; c < 10; ++c){ lg[c] = acc[c] + b2s[c]; m = fmaxf(m, lg[c]); }
        float sum = 0.0f;
        #pragma unroll
        for (int c = 0; c < 10; ++c) sum += expf(lg[c] - m);
        float ls = logf(sum);
        if (lane < 10) out[(size_t)b*10 + lane] = lg[lane] - m - ls;
    }
}

extern "C" void kernel_launch(void* const* d_in, const int* in_sizes, int n_in,
                              void* d_out, int out_size, void* d_ws, size_t ws_size,
                              hipStream_t stream){
    const float* x   = (const float*)d_in[0];
    const float* c1w = (const float*)d_in[1];
    const float* c1b = (const float*)d_in[2];
    const float* c2w = (const float*)d_in[3];
    const float* c2b = (const float*)d_in[4];
    const float* f1w = (const float*)d_in[5];
    const float* f1b = (const float*)d_in[6];
    const float* f2w = (const float*)d_in[7];
    const float* f2b = (const float*)d_in[8];
    int B = in_sizes[0] / 784;

    float* ws = (float*)d_ws;
    unsigned int* enc = (unsigned int*)d_ws + 4;
    ushort_t* w1bf = (ushort_t*)((char*)d_ws + W1BF_BYTE);
    ushort_t* w2bf = (ushort_t*)((char*)d_ws + W2BF_BYTE);
    ushort_t* w3bf = (ushort_t*)((char*)d_ws + W3BF_BYTE);
    ushort_t* q1cl = (ushort_t*)((char*)d_ws + Q1_BYTE);
    ushort_t* q2bf = (ushort_t*)((char*)d_ws + Q2_BYTE);
    unsigned char* q3 = (unsigned char*)d_ws + Q3_BYTE;
    float* out = (float*)d_out;

    k_init<<<1, 64, 0, stream>>>(enc);
    k_minmax<<<72, TPB, 0, stream>>>(c1w, c1b, c2w, c2b, f1w, f1b, enc);
    k_make_eff<<<(N_EFF + TPB - 1)/TPB, TPB, 0, stream>>>(c1w, c1b, c2w, c2b, f1w, f1b, enc, ws, w1bf, w2bf, w3bf);
    k_conv1<<<B, TPB, 0, stream>>>(x, w1bf, ws, q1cl);
    k_conv2<<<(B + CONV2_G - 1)/CONV2_G, TPB, 0, stream>>>(q1cl, w2bf, ws, q2bf, B);
    dim3 g_fc1(8, B/64);
    k_fc1<<<g_fc1, TPB, 0, stream>>>(q2bf, w3bf, ws, q3, B);
    k_fc2<<<(B + 15)/16, TPB, 0, stream>>>(q3, f2w, f2b, out, B);
}

// Round 5
// 215.372 us; speedup vs baseline: 1.5588x; 1.5588x over previous
//
#include <hip/hip_runtime.h>
#include <cmath>

#define TPB 256
typedef float floatx4 __attribute__((ext_vector_type(4)));
typedef __bf16 bf16x8 __attribute__((ext_vector_type(8)));
typedef unsigned short ushort8 __attribute__((ext_vector_type(8)));
typedef unsigned short ushort_t;

// ---------- workspace layout ----------
// float units: [0]=sc2 (S_N1*s_w2), [1]=sc3 (S_N2*s_w3), [2]=K1 (S_X1*s_w1/S_N1)
// uint units 4..15: enc min/max (6 pairs)
#define OFF_B1 520       // 20  f32  (pre-divided by S_N1)
#define OFF_B2 544       // 50  f32
#define OFF_B3 600       // 500 f32
#define W1BF_BYTE 6144       // [32][32] u16 int weights (conv1)
#define W2BF_BYTE 8192       // [20 chunks][64 co][32 k] u16 int weights (conv2), 81920 B
#define W3BF_BYTE 131072     // [512][800]  u16 int weights (fc1)
#define Q1_BYTE  1048576ULL  // [B][pixel(144)][ci(20)] bf16 (channels-last)
#define Q2_BYTE  25165824ULL // [B][800] bf16
#define Q3_BYTE  33554432ULL // [B][500] u8

#define S_X1 (3.5f/255.0f)
#define ZP_X1 36.0f
#define S_N1 (6.0f/255.0f)
#define S_N2 (8.0f/255.0f)
#define S_N3 (10.0f/255.0f)

#define CONV2_G 4

__device__ inline unsigned int enc_f(float f){
    unsigned int u = __float_as_uint(f);
    return (u & 0x80000000u) ? ~u : (u | 0x80000000u);
}
__device__ inline float dec_f(unsigned int e){
    unsigned int u = (e & 0x80000000u) ? (e & 0x7fffffffu) : ~e;
    return __uint_as_float(u);
}
__device__ inline void sczp(float mn, float mx, float& s, float& zp){
    s = (mx - mn) / 255.0f;
    zp = truncf(fminf(fmaxf(0.0f - mn / s, 0.0f), 255.0f));
}
__device__ inline float qclip(float x, float s, float zp){
    return rintf(fminf(fmaxf(zp + x / s, 0.0f), 255.0f));
}
// exact bf16 bits for integer-valued floats |v| < 256
__device__ inline ushort_t bfbits(float v){
    return (ushort_t)(__float_as_uint(v) >> 16);
}

__global__ void k_init(unsigned int* enc){
    int i = threadIdx.x;
    if (i < 6){ enc[2*i] = 0xFFFFFFFFu; enc[2*i+1] = 0u; }
}

__global__ __launch_bounds__(TPB) void k_minmax(
        const float* c1w, const float* c1b, const float* c2w, const float* c2b,
        const float* f1w, const float* f1b, unsigned int* enc){
    __shared__ float smn[TPB], smx[TPB];
    int bb = blockIdx.x, tid = threadIdx.x;
    const float* src; int n, t, sub, nsub;
    if      (bb == 0){ src=c1w; n=500;    t=0; sub=0;     nsub=1;  }
    else if (bb == 1){ src=c1b; n=20;     t=1; sub=0;     nsub=1;  }
    else if (bb <  6){ src=c2w; n=25000;  t=2; sub=bb-2;  nsub=4;  }
    else if (bb == 6){ src=c2b; n=50;     t=3; sub=0;     nsub=1;  }
    else if (bb < 71){ src=f1w; n=400000; t=4; sub=bb-7;  nsub=64; }
    else             { src=f1b; n=500;    t=5; sub=0;     nsub=1;  }
    float mn = INFINITY, mx = -INFINITY;
    for (int i = sub*TPB + tid; i < n; i += nsub*TPB){
        float v = src[i]; mn = fminf(mn, v); mx = fmaxf(mx, v);
    }
    smn[tid] = mn; smx[tid] = mx; __syncthreads();
    for (int s = TPB/2; s > 0; s >>= 1){
        if (tid < s){
            smn[tid] = fminf(smn[tid], smn[tid+s]);
            smx[tid] = fmaxf(smx[tid], smx[tid+s]);
        }
        __syncthreads();
    }
    if (tid == 0){
        atomicMin(&enc[2*t],   enc_f(smn[0]));
        atomicMax(&enc[2*t+1], enc_f(smx[0]));
    }
}

// w2bt chunk packing (20 chunks of K=32):
//   main c in 0..12:   oct q -> tap = 2c + (q>>1), ci = (q&1)*8 + jj   (tap 25 -> zero)
//   residue c in 13..19: oct q -> tap = 4(c-13) + q, ci = 16 + jj (jj<4; jj>=4 -> zero)
#define N_EFF 452157
__global__ __launch_bounds__(TPB) void k_make_eff(
        const float* c1w, const float* c1b, const float* c2w, const float* c2b,
        const float* f1w, const float* f1b, const unsigned int* enc,
        float* ws, ushort_t* w1bf, ushort_t* w2bf, ushort_t* w3bf){
    int i = blockIdx.x * TPB + threadIdx.x;
    if (i >= N_EFF) return;
    if (i < 1024){                   // w1bf: [n(32)][k(32)] integer weights
        int n = i >> 5, k = i & 31;
        float v = 0.0f;
        if (n < 20 && k < 25){
            float s, zp; sczp(dec_f(enc[0]), dec_f(enc[1]), s, zp);
            v = qclip(c1w[n*25 + k], s, zp) - zp;
        }
        w1bf[i] = bfbits(v);
    } else if (i < 1044){            // b1 pre-divided by S_N1
        int j = i - 1024;
        float s, zp; sczp(dec_f(enc[2]), dec_f(enc[3]), s, zp);
        ws[OFF_B1 + j] = (s * (qclip(c1b[j], s, zp) + zp)) / S_N1;
    } else if (i < 42004){           // w2bt chunk-packed
        int j = i - 1044;
        int c = j >> 11, r = j & 2047, co = r >> 5, k = r & 31;
        int q = k >> 3, jj = k & 7;
        int tap, ci; bool valid;
        if (c < 13){ tap = 2*c + (q>>1); ci = (q&1)*8 + jj; valid = (tap < 25); }
        else       { tap = 4*(c-13) + q; ci = 16 + jj;      valid = (tap < 25) && (jj < 4); }
        valid = valid && (co < 50);
        float v = 0.0f;
        if (valid){
            float s, zp; sczp(dec_f(enc[4]), dec_f(enc[5]), s, zp);
            v = qclip(c2w[(co*20 + ci)*25 + tap], s, zp) - zp;
        }
        w2bf[j] = bfbits(v);
    } else if (i < 42054){
        int j = i - 42004;
        float s, zp; sczp(dec_f(enc[6]), dec_f(enc[7]), s, zp);
        ws[OFF_B2 + j] = s * (qclip(c2b[j], s, zp) + zp);
    } else if (i < 451654){          // w3bf: [n(512)][k(800)]
        int j = i - 42054;
        int n = j / 800, k = j - 800*n;
        float v = 0.0f;
        if (n < 500){
            float s, zp; sczp(dec_f(enc[8]), dec_f(enc[9]), s, zp);
            v = qclip(f1w[n*800 + k], s, zp) - zp;
        }
        w3bf[j] = bfbits(v);
    } else if (i < 452154){
        int j = i - 451654;
        float s, zp; sczp(dec_f(enc[10]), dec_f(enc[11]), s, zp);
        ws[OFF_B3 + j] = s * (qclip(f1b[j], s, zp) + zp);
    } else if (i == 452154){
        float s, zp; sczp(dec_f(enc[4]), dec_f(enc[5]), s, zp);
        ws[0] = S_N1 * s;            // conv2 combined scale
    } else if (i == 452155){
        float s, zp; sczp(dec_f(enc[8]), dec_f(enc[9]), s, zp);
        ws[1] = S_N2 * s;            // fc1 combined scale
    } else {
        float s, zp; sczp(dec_f(enc[0]), dec_f(enc[1]), s, zp);
        ws[2] = (S_X1 * s) / S_N1;   // conv1 combined scale, pre-divided
    }
}

// conv1 via bf16 MFMA implicit GEMM -> channels-last q1cl[B][pixel(144)][ci(20)] bf16 ints
__global__ __launch_bounds__(TPB) void k_conv1(const float* x, const ushort_t* w1bf,
                                               const float* ws, ushort_t* q1cl){
    __shared__ ushort_t xs[784];
    __shared__ unsigned char hb[5760];   // [oh(24)*12+pw][ch(20)] horizontal pool maxes
    int b = blockIdx.x, tid = threadIdx.x;
    int lane = tid & 63, wv = tid >> 6;
    int ln = lane & 15, quad = lane >> 4;

    const float* xb = x + (size_t)b * 784;
    for (int i = tid; i < 784; i += TPB){
        float v = xb[i];
        float q = rintf(fminf(fmaxf(ZP_X1 + v / S_X1, 0.0f), 255.0f));
        xs[i] = bfbits(q - ZP_X1);
    }

    int offj[8]; bool vj[8];
    #pragma unroll
    for (int j = 0; j < 8; ++j){
        int k = quad*8 + j;
        vj[j] = (k < 25);
        int kh = k / 5, kw = k - 5*kh;
        offj[j] = vj[j] ? (kh*28 + kw) : 0;
    }

    ushort8 bw0 = *(const ushort8*)(w1bf + ln*32 + quad*8);
    ushort8 bw1 = *(const ushort8*)(w1bf + (16 + ln)*32 + quad*8);
    bf16x8 bf0 = __builtin_bit_cast(bf16x8, bw0);
    bf16x8 bf1 = __builtin_bit_cast(bf16x8, bw1);

    float K1 = ws[2];
    float B1_0 = ws[OFF_B1 + ln];
    float B1_1 = (ln < 4) ? ws[OFF_B1 + 16 + ln] : 0.0f;
    __syncthreads();

    for (int i = 0; i < 9; ++i){
        int mt = 9*wv + i;
        int m = mt*16 + ln;
        int oh = m / 24, ow = m - 24*oh;
        int base = oh*28 + ow;
        ushort8 aw;
        #pragma unroll
        for (int j = 0; j < 8; ++j)
            aw[j] = vj[j] ? xs[base + offj[j]] : (ushort_t)0;
        bf16x8 af = __builtin_bit_cast(bf16x8, aw);
        floatx4 z = (floatx4){0.f,0.f,0.f,0.f};
        floatx4 a0 = __builtin_amdgcn_mfma_f32_16x16x32_bf16(af, bf0, z, 0, 0, 0);
        floatx4 a1 = __builtin_amdgcn_mfma_f32_16x16x32_bf16(af, bf1, z, 0, 0, 0);

        int m0 = mt*16 + quad*4;
        int oh0 = m0 / 24, owp = (m0 - 24*oh0) >> 1;
        int hbase = (oh0*12 + owp)*20;
        {
            float q[4];
            #pragma unroll
            for (int r = 0; r < 4; ++r){
                float y = fmaxf(fmaf(a0[r], K1, B1_0), 0.0f);
                q[r] = fmodf(rintf(y), 256.0f);
            }
            hb[hbase + ln]      = (unsigned char)fmaxf(q[0], q[1]);
            hb[hbase + 20 + ln] = (unsigned char)fmaxf(q[2], q[3]);
        }
        if (ln < 4){
            float q[4];
            #pragma unroll
            for (int r = 0; r < 4; ++r){
                float y = fmaxf(fmaf(a1[r], K1, B1_1), 0.0f);
                q[r] = fmodf(rintf(y), 256.0f);
            }
            hb[hbase + 16 + ln]      = (unsigned char)fmaxf(q[0], q[1]);
            hb[hbase + 36 + ln]      = (unsigned char)fmaxf(q[2], q[3]);
        }
    }
    __syncthreads();

    // vertical pool + write CHANNELS-LAST: o = pixel*20 + c
    for (int o = tid; o < 2880; o += TPB){
        int p = o / 20, c = o - 20*p;
        int ph = p / 12, pw = p - 12*ph;
        unsigned char t_ = hb[((2*ph)*12 + pw)*20 + c];
        unsigned char u_ = hb[((2*ph+1)*12 + pw)*20 + c];
        float m_ = (float)(t_ > u_ ? t_ : u_);
        q1cl[(size_t)b*2880 + o] = bfbits(m_);
    }
}

// conv2 v4: channels-last LDS image [pixel(144)][ci24], wave owns one nt (16 co),
// 4 m-tiles, acc = 16 VGPRs. B-frags stream from L2 per chunk. Barrier-free K-loop,
// double-buffered image staging, 1 barrier/image, G images/block.
__global__ __launch_bounds__(TPB) void k_conv2(const ushort_t* q1cl, const ushort_t* w2bt,
                                               const float* ws, ushort_t* q2bf, int B){
    __shared__ __align__(16) ushort_t xs[2][144*24];
    int tid = threadIdx.x;
    int lane = tid & 63, wv = tid >> 6;
    int ln = lane & 15, quad = lane >> 4;

    // zero the ci-pad columns (dwords 10,11 of each pixel row) in both buffers
    if (tid < 144){
        ((unsigned int*)xs[0])[tid*12 + 10] = 0u;
        ((unsigned int*)xs[0])[tid*12 + 11] = 0u;
        ((unsigned int*)xs[1])[tid*12 + 10] = 0u;
        ((unsigned int*)xs[1])[tid*12 + 11] = 0u;
    }

    // per-lane A addressing (u16 units): addr = abase[mt] + aoff[c]
    int abase[4];
    #pragma unroll
    for (int mt = 0; mt < 4; ++mt)
        abase[mt] = (24*mt + (ln>>3)*12 + (ln&7)) * 24;
    int aoff[20];
    #pragma unroll
    for (int c = 0; c < 20; ++c){
        int tap, inner;
        if (c < 13){ tap = 2*c + (quad>>1); inner = (quad&1)*8; }
        else       { tap = 4*(c-13) + quad; inner = 16; }
        int pt = 0;
        if (tap < 25){ int kh = tap/5, kw = tap-5*kh; pt = kh*12 + kw; }
        // tap>=25 -> pt=0 (weights are zero there, product is 0)
        aoff[c] = pt*24 + inner;
    }

    float sc2 = ws[0];
    int co = wv*16 + ln;
    float bias = (co < 50) ? ws[OFF_B2 + co] : 0.0f;
    const ushort_t* bsrc = w2bt + (size_t)co*32 + quad*8;

    int b0 = blockIdx.x * CONV2_G;
    // stage image 0
    {
        const unsigned int* src = (const unsigned int*)(q1cl + (size_t)b0*2880);
        unsigned int* dst = (unsigned int*)xs[0];
        for (int i = tid; i < 1440; i += TPB){
            int p = i / 10, d = i - 10*p;
            dst[p*12 + d] = src[i];
        }
    }
    __syncthreads();

    for (int g = 0; g < CONV2_G; ++g){
        int b = b0 + g;
        if (b >= B) break;

        // stage next image into the other buffer (no barrier needed vs compute)
        if (g + 1 < CONV2_G && b + 1 < B){
            const unsigned int* src = (const unsigned int*)(q1cl + (size_t)(b+1)*2880);
            unsigned int* dst = (unsigned int*)xs[(g+1)&1];
            for (int i = tid; i < 1440; i += TPB){
                int p = i / 10, d = i - 10*p;
                dst[p*12 + d] = src[i];
            }
        }

        const ushort_t* cur = xs[g & 1];
        floatx4 acc[4];
        #pragma unroll
        for (int mt = 0; mt < 4; ++mt) acc[mt] = (floatx4){0.f,0.f,0.f,0.f};

        // barrier-free K-loop: 20 chunks x (1 global B-load + 4 LDS A-reads + 4 MFMAs)
        #pragma unroll
        for (int c = 0; c < 20; ++c){
            ushort8 bw = *(const ushort8*)(bsrc + c*2048);
            bf16x8 bfr = __builtin_bit_cast(bf16x8, bw);
            #pragma unroll
            for (int mt = 0; mt < 4; ++mt){
                ushort8 aw = *(const ushort8*)(cur + abase[mt] + aoff[c]);
                acc[mt] = __builtin_amdgcn_mfma_f32_16x16x32_bf16(
                              __builtin_bit_cast(bf16x8, aw), bfr, acc[mt], 0, 0, 0);
            }
        }

        // epilogue: quantize, 2x2 pool (in-reg horizontal, shfl_xor(32) vertical)
        #pragma unroll
        for (int mt = 0; mt < 4; ++mt){
            float q[4];
            #pragma unroll
            for (int r = 0; r < 4; ++r){
                float y = fmaxf((acc[mt][r]*sc2 + bias) / S_N2, 0.0f);
                q[r] = fmodf(rintf(y), 256.0f);
            }
            float h0 = fmaxf(q[0], q[1]), h1 = fmaxf(q[2], q[3]);
            float v0 = fmaxf(h0, __shfl_xor(h0, 32));
            float v1 = fmaxf(h1, __shfl_xor(h1, 32));
            if (quad < 2 && co < 50){
                size_t base = (size_t)b*800 + co*16 + mt*4 + quad*2;
                q2bf[base]     = bfbits(v0);
                q2bf[base + 1] = bfbits(v1);
            }
        }
        __syncthreads();   // staged next buffer ready; current buffer free
    }
}

// fc1 via bf16 MFMA GEMM: [B,800] x [512,800]^T, tile 64x64, K-chunk 32, dbuf LDS.
__global__ __launch_bounds__(TPB) void k_fc1(const ushort_t* q2bf, const ushort_t* w3bf,
                                             const float* ws, unsigned char* q3, int B){
    __shared__ ushort_t As[2][64*40];
    int tid = threadIdx.x;
    int n0b = blockIdx.x * 64;
    int b0  = blockIdx.y * 64;
    int lane = tid & 63, wv = tid >> 6;
    int ln = lane & 15, quad = lane >> 4;
    int n0 = n0b + wv*16;
    int lrow = tid >> 2, lk = (tid & 3) * 8;
    const ushort_t* asrc = q2bf + (size_t)(b0 + lrow)*800 + lk;
    ushort_t* adst0 = &As[0][0] + lrow*40 + lk;
    ushort_t* adst1 = &As[1][0] + lrow*40 + lk;

    floatx4 acc[4];
    #pragma unroll
    for (int mt = 0; mt < 4; ++mt) acc[mt] = (floatx4){0.f,0.f,0.f,0.f};

    *(ushort8*)adst0 = *(const ushort8*)asrc;
    __syncthreads();

    for (int c = 0; c < 25; ++c){
        const ushort_t* cur = &As[c & 1][0];
        ushort8 tn;
        bool pf = (c + 1 < 25);
        if (pf) tn = *(const ushort8*)(asrc + (c + 1)*32);
        ushort8 bw = *(const ushort8*)(w3bf + (size_t)(n0 + ln)*800 + c*32 + quad*8);
        bf16x8 bfr = __builtin_bit_cast(bf16x8, bw);
        #pragma unroll
        for (int mt = 0; mt < 4; ++mt){
            ushort8 aw = *(const ushort8*)(cur + (16*mt + ln)*40 + quad*8);
            acc[mt] = __builtin_amdgcn_mfma_f32_16x16x32_bf16(
                          __builtin_bit_cast(bf16x8, aw), bfr, acc[mt], 0, 0, 0);
        }
        if (pf) *(ushort8*)(((c + 1) & 1) ? adst1 : adst0) = tn;
        __syncthreads();
    }

    float sc3 = ws[1];
    int n = n0 + ln;
    if (n < 500){
        float bias = ws[OFF_B3 + n];
        #pragma unroll
        for (int mt = 0; mt < 4; ++mt){
            #pragma unroll
            for (int r = 0; r < 4; ++r){
                int m = 16*mt + 4*quad + r;
                float y = fmaxf((acc[mt][r] * sc3 + bias) / S_N3, 0.0f);
                float q = fmodf(rintf(y), 256.0f);
                q3[(size_t)(b0 + m)*500 + n] = (unsigned char)q;
            }
        }
    }
}

// fc2 (dequant + [B,500]x[10,500]^T + bias) + log_softmax. 16 rows/block, w2 in LDS.
__global__ __launch_bounds__(TPB) void k_fc2(const unsigned char* q3, const float* w2,
                                             const float* b2, float* out, int B){
    __shared__ float w2s[5000];
    __shared__ float b2s[10];
    int tid = threadIdx.x;
    for (int i = tid; i < 5000; i += TPB) w2s[i] = w2[i];
    if (tid < 10) b2s[tid] = b2[tid];
    __syncthreads();
    int lane = tid & 63, wv = tid >> 6;
    for (int rr = 0; rr < 4; ++rr){
        int b = blockIdx.x*16 + wv*4 + rr;
        if (b >= B) break;
        float acc[10];
        #pragma unroll
        for (int c = 0; c < 10; ++c) acc[c] = 0.0f;
        for (int k = lane; k < 500; k += 64){
            float xf = S_N3 * (float)q3[(size_t)b*500 + k];
            #pragma unroll
            for (int c = 0; c < 10; ++c)
                acc[c] = fmaf(xf, w2s[c*500 + k], acc[c]);
        }
        #pragma unroll
        for (int off = 32; off > 0; off >>= 1)
            #pragma unroll
            for (int c = 0; c < 10; ++c)
                acc[c] += __shfl_xor(acc[c], off);
        float lg[10], m = -INFINITY;
        #pragma unroll
        for (int c = 0; c < 10; ++c){ lg[c] = acc[c] + b2s[c]; m = fmaxf(m, lg[c]); }
        float sum = 0.0f;
        #pragma unroll
        for (int c = 0; c < 10; ++c) sum += expf(lg[c] - m);
        float ls = logf(sum);
        if (lane < 10) out[(size_t)b*10 + lane] = lg[lane] - m - ls;
    }
}

extern "C" void kernel_launch(void* const* d_in, const int* in_sizes, int n_in,
                              void* d_out, int out_size, void* d_ws, size_t ws_size,
                              hipStream_t stream){
    const float* x   = (const float*)d_in[0];
    const float* c1w = (const float*)d_in[1];
    const float* c1b = (const float*)d_in[2];
    const float* c2w = (const float*)d_in[3];
    const float* c2b = (const float*)d_in[4];
    const float* f1w = (const float*)d_in[5];
    const float* f1b = (const float*)d_in[6];
    const float* f2w = (const float*)d_in[7];
    const float* f2b = (const float*)d_in[8];
    int B = in_sizes[0] / 784;

    float* ws = (float*)d_ws;
    unsigned int* enc = (unsigned int*)d_ws + 4;
    ushort_t* w1bf = (ushort_t*)((char*)d_ws + W1BF_BYTE);
    ushort_t* w2bf = (ushort_t*)((char*)d_ws + W2BF_BYTE);
    ushort_t* w3bf = (ushort_t*)((char*)d_ws + W3BF_BYTE);
    ushort_t* q1cl = (ushort_t*)((char*)d_ws + Q1_BYTE);
    ushort_t* q2bf = (ushort_t*)((char*)d_ws + Q2_BYTE);
    unsigned char* q3 = (unsigned char*)d_ws + Q3_BYTE;
    float* out = (float*)d_out;

    k_init<<<1, 64, 0, stream>>>(enc);
    k_minmax<<<72, TPB, 0, stream>>>(c1w, c1b, c2w, c2b, f1w, f1b, enc);
    k_make_eff<<<(N_EFF + TPB - 1)/TPB, TPB, 0, stream>>>(c1w, c1b, c2w, c2b, f1w, f1b, enc, ws, w1bf, w2bf, w3bf);
    k_conv1<<<B, TPB, 0, stream>>>(x, w1bf, ws, q1cl);
    k_conv2<<<(B + CONV2_G - 1)/CONV2_G, TPB, 0, stream>>>(q1cl, w2bf, ws, q2bf, B);
    dim3 g_fc1(8, B/64);
    k_fc1<<<g_fc1, TPB, 0, stream>>>(q2bf, w3bf, ws, q3, B);
    k_fc2<<<(B + 15)/16, TPB, 0, stream>>>(q3, f2w, f2b, out, B);
}